// Round 2
// baseline (987.232 us; speedup 1.0000x reference)
//
#include <hip/hip_runtime.h>
#include <hip/hip_bf16.h>

// Problem constants (fixed by setup_inputs)
#define NQ   5440
#define NB   8
#define DIM  256
#define NH   8
#define CHN  32
#define NLV  4
#define NPT  4
#define MTOT (NB * NQ)   // 43520

// C[m, j] = sum_k A[m, k] * W[j, k] + bias[j]
// A: (MTOT, 256), W: (Ncols, 256), C: (MTOT, Ncols). K = 256 fixed.
// 64x64 tile, TK = 64, 256 threads, 4x4 accum per thread.
__global__ __launch_bounds__(256) void gemm_tn(const float* __restrict__ A,
                                               const float* __restrict__ W,
                                               const float* __restrict__ bias,
                                               float* __restrict__ C, int Ncols) {
    __shared__ float As[64][65];   // [k][m], +1 pad: conflict-free
    __shared__ float Ws[64][65];   // [k][n]

    const int t = threadIdx.x;
    const int rowBase = blockIdx.x * 64;
    const int colBase = blockIdx.y * 64;
    const int tx = t & 15;   // -> col
    const int ty = t >> 4;   // -> row

    float acc[4][4] = {{0.f}};

    for (int k0 = 0; k0 < 256; k0 += 64) {
#pragma unroll
        for (int i = 0; i < 16; ++i) {
            int lin = t + i * 256;          // 0..4095
            int kk = lin & 63;
            int rr = lin >> 6;
            As[kk][rr] = A[(size_t)(rowBase + rr) * DIM + k0 + kk];
            Ws[kk][rr] = W[(size_t)(colBase + rr) * DIM + k0 + kk];
        }
        __syncthreads();
#pragma unroll 8
        for (int kk = 0; kk < 64; ++kk) {
            float a[4], w[4];
#pragma unroll
            for (int i = 0; i < 4; ++i) a[i] = As[kk][ty + i * 16];
#pragma unroll
            for (int j = 0; j < 4; ++j) w[j] = Ws[kk][tx + j * 16];
#pragma unroll
            for (int i = 0; i < 4; ++i)
#pragma unroll
                for (int j = 0; j < 4; ++j) acc[i][j] += a[i] * w[j];
        }
        __syncthreads();
    }

#pragma unroll
    for (int i = 0; i < 4; ++i) {
        int row = rowBase + ty + i * 16;
#pragma unroll
        for (int j = 0; j < 4; ++j) {
            int col = colBase + tx + j * 16;
            C[(size_t)row * Ncols + col] = acc[i][j] + bias[col];
        }
    }
}

// One block per (n, q). Phase A (threads 0..127): coords + softmax for
// (h, l, p). Phase B (all 256): bilinear gather+accumulate per (h, c).
// NOTE: `sampled` may alias `off` (same rows): each block reads its own off
// row in phase A, syncs, then writes the same row as sampled in phase B.
__global__ __launch_bounds__(256) void sample_kernel(
    const float* __restrict__ refp,            // (N, Lq, L, 2)
    const float* __restrict__ off,             // (N*Lq, 256)
    const float* __restrict__ attn,            // (N*Lq, 128)
    const float* __restrict__ value,           // (N, Lin, 256) d = h*32+c
    const int* __restrict__ shapes,            // (L, 2) [H, W]
    const int* __restrict__ starts,            // (L,)
    float* __restrict__ sampled)               // (N*Lq, 256)
{
    const int q = blockIdx.x;       // n*Lq + lq
    const int n = q / NQ;
    const int t = threadIdx.x;

    __shared__ float sx[128], sy[128], sw[128];
    __shared__ int sH[NLV], sW[NLV], sS[NLV];

    if (t >= 128 && t < 128 + NLV) {
        int l = t - 128;
        sH[l] = shapes[2 * l];
        sW[l] = shapes[2 * l + 1];
        sS[l] = starts[l];
    }
    if (t < 128) {
        const int h = t >> 4, lp = t & 15, l = lp >> 2, p = lp & 3;
        const float Wl = (float)shapes[2 * l + 1];
        const float Hl = (float)shapes[2 * l];
        const float rx = refp[((size_t)q * NLV + l) * 2 + 0];
        const float ry = refp[((size_t)q * NLV + l) * 2 + 1];
        const int oidx = ((h * NLV + l) * NPT + p) * 2;
        const float ox = off[(size_t)q * DIM + oidx];
        const float oy = off[(size_t)q * DIM + oidx + 1];
        const float x = (rx + ox / Wl) * Wl - 0.5f;
        const float y = (ry + oy / Hl) * Hl - 0.5f;

        float logit = attn[(size_t)q * 128 + h * 16 + lp];
        // softmax over the 16-lane group (one head)
        float m = logit;
#pragma unroll
        for (int s = 8; s >= 1; s >>= 1) m = fmaxf(m, __shfl_xor(m, s, 16));
        float e = __expf(logit - m);
        float ssum = e;
#pragma unroll
        for (int s = 8; s >= 1; s >>= 1) ssum += __shfl_xor(ssum, s, 16);
        sx[t] = x;
        sy[t] = y;
        sw[t] = e / ssum;
    }
    __syncthreads();

    const int h = t >> 5, c = t & 31;
    const float* vbase = value + (size_t)n * NQ * DIM + h * CHN + c;
    float acc = 0.f;
#pragma unroll
    for (int l = 0; l < NLV; ++l) {
        const int Wl = sW[l], Hl = sH[l];
        const float* vb = vbase + (size_t)sS[l] * DIM;
#pragma unroll
        for (int p = 0; p < NPT; ++p) {
            const int li = h * 16 + l * NPT + p;
            const float x = sx[li], y = sy[li], w = sw[li];
            const float xf = floorf(x), yf = floorf(y);
            const int ix = (int)xf, iy = (int)yf;
            const float wx = x - xf, wy = y - yf;
            const bool vx0 = (ix >= 0) && (ix < Wl);
            const bool vx1 = (ix >= -1) && (ix < Wl - 1);
            const bool vy0 = (iy >= 0) && (iy < Hl);
            const bool vy1 = (iy >= -1) && (iy < Hl - 1);
            const float v00 = (vx0 && vy0) ? vb[(size_t)(iy * Wl + ix) * DIM] : 0.f;
            const float v10 = (vx1 && vy0) ? vb[(size_t)(iy * Wl + ix + 1) * DIM] : 0.f;
            const float v01 = (vx0 && vy1) ? vb[(size_t)((iy + 1) * Wl + ix) * DIM] : 0.f;
            const float v11 = (vx1 && vy1) ? vb[(size_t)((iy + 1) * Wl + ix + 1) * DIM] : 0.f;
            const float s = v00 * (1.f - wx) * (1.f - wy) + v10 * wx * (1.f - wy) +
                            v01 * (1.f - wx) * wy + v11 * wx * wy;
            acc += w * s;
        }
    }
    sampled[(size_t)q * DIM + t] = acc;
}

extern "C" void kernel_launch(void* const* d_in, const int* in_sizes, int n_in,
                              void* d_out, int out_size, void* d_ws, size_t ws_size,
                              hipStream_t stream) {
    const float* query  = (const float*)d_in[0];
    const float* refp   = (const float*)d_in[1];
    const float* inputf = (const float*)d_in[2];
    const int* shapes   = (const int*)d_in[3];
    const int* starts   = (const int*)d_in[4];
    const float* W_off  = (const float*)d_in[5];
    const float* b_off  = (const float*)d_in[6];
    const float* W_attn = (const float*)d_in[7];
    const float* b_attn = (const float*)d_in[8];
    const float* W_val  = (const float*)d_in[9];
    const float* b_val  = (const float*)d_in[10];
    const float* W_out  = (const float*)d_in[11];
    const float* b_out  = (const float*)d_in[12];
    float* out = (float*)d_out;

    float* ws = (float*)d_ws;
    float* v_val  = ws;                              // MTOT*256
    float* v_off  = v_val + (size_t)MTOT * DIM;      // MTOT*256
    float* v_attn = v_off + (size_t)MTOT * DIM;      // MTOT*128
    float* v_samp = v_off;                           // aliases v_off (safe, see kernel)

    dim3 blk(256);
    gemm_tn<<<dim3(MTOT / 64, 4), blk, 0, stream>>>(inputf, W_val, b_val, v_val, 256);
    gemm_tn<<<dim3(MTOT / 64, 4), blk, 0, stream>>>(query, W_off, b_off, v_off, 256);
    gemm_tn<<<dim3(MTOT / 64, 2), blk, 0, stream>>>(query, W_attn, b_attn, v_attn, 128);
    sample_kernel<<<dim3(MTOT), blk, 0, stream>>>(refp, v_off, v_attn, v_val,
                                                  shapes, starts, v_samp);
    gemm_tn<<<dim3(MTOT / 64, 4), blk, 0, stream>>>(v_samp, W_out, b_out, out, 256);
}

// Round 3
// 359.079 us; speedup vs baseline: 2.7493x; 2.7493x over previous
//
#include <hip/hip_runtime.h>
#include <hip/hip_bf16.h>

// Problem constants (fixed by setup_inputs)
#define NQ   5440
#define NB   8
#define DIM  256
#define NH   8
#define CHN  32
#define NLV  4
#define NPT  4
#define MTOT (NB * NQ)   // 43520

typedef __attribute__((ext_vector_type(8))) short s16x8;   // 8 bf16 in 4 VGPRs
typedef __attribute__((ext_vector_type(4))) float f32x4;

__device__ __forceinline__ short f2bf(float x) {
    union { __hip_bfloat16 b; short s; } u;
    u.b = __float2bfloat16(x);
    return u.s;
}

#define LDSK 72   // bf16 elems per LDS row (64 + 8 pad -> 144B stride, 16B aligned, 2-way max bank alias)

// C[m, j] = sum_k A[m, k] * W[j, k] + bias[j]   (A, W both K-contiguous = "B^T" form)
// 128x128 tile, BK=64, 256 threads (4 waves, 2x2), 4x4 16x16x32 bf16 MFMA frags/wave.
// fp32 -> bf16 conversion fused into LDS staging.
__global__ __launch_bounds__(256) void gemm_mfma(const float* __restrict__ A,
                                                 const float* __restrict__ W,
                                                 const float* __restrict__ bias,
                                                 float* __restrict__ C, int Ncols) {
    __shared__ short As[128 * LDSK];
    __shared__ short Ws[128 * LDSK];

    const int t = threadIdx.x;
    const int lane = t & 63, wave = t >> 6;
    const int wm = wave >> 1, wn = wave & 1;
    const int rowBase = blockIdx.x * 128, colBase = blockIdx.y * 128;
    const int lr = lane & 15, quad = lane >> 4;

    f32x4 acc[4][4];
#pragma unroll
    for (int i = 0; i < 4; ++i)
#pragma unroll
        for (int j = 0; j < 4; ++j)
#pragma unroll
            for (int r = 0; r < 4; ++r) acc[i][j][r] = 0.f;

    for (int k0 = 0; k0 < 256; k0 += 64) {
        // stage A-tile and W-tile (128 rows x 64 k) as bf16 into LDS
#pragma unroll
        for (int i = 0; i < 4; ++i) {
            int c = t + i * 256;            // 0..1023 chunk id (8 floats each)
            int r = c >> 3, kc = (c & 7) * 8;
            const float* pa = A + (size_t)(rowBase + r) * DIM + k0 + kc;
            const float* pw = W + (size_t)(colBase + r) * DIM + k0 + kc;
            f32x4 a0 = *(const f32x4*)pa, a1 = *(const f32x4*)(pa + 4);
            f32x4 w0 = *(const f32x4*)pw, w1 = *(const f32x4*)(pw + 4);
            s16x8 av, wv;
#pragma unroll
            for (int e = 0; e < 4; ++e) {
                av[e] = f2bf(a0[e]);
                av[e + 4] = f2bf(a1[e]);
                wv[e] = f2bf(w0[e]);
                wv[e + 4] = f2bf(w1[e]);
            }
            *(s16x8*)&As[r * LDSK + kc] = av;
            *(s16x8*)&Ws[r * LDSK + kc] = wv;
        }
        __syncthreads();
#pragma unroll
        for (int kk = 0; kk < 64; kk += 32) {
            s16x8 afr[4], wfr[4];
#pragma unroll
            for (int i = 0; i < 4; ++i)
                afr[i] = *(const s16x8*)&As[(wm * 64 + i * 16 + lr) * LDSK + kk + quad * 8];
#pragma unroll
            for (int j = 0; j < 4; ++j)
                wfr[j] = *(const s16x8*)&Ws[(wn * 64 + j * 16 + lr) * LDSK + kk + quad * 8];
#pragma unroll
            for (int i = 0; i < 4; ++i)
#pragma unroll
                for (int j = 0; j < 4; ++j)
                    acc[i][j] = __builtin_amdgcn_mfma_f32_16x16x32_bf16(
                        afr[i], wfr[j], acc[i][j], 0, 0, 0);
        }
        __syncthreads();
    }

    float bj[4];
#pragma unroll
    for (int j = 0; j < 4; ++j) bj[j] = bias[colBase + wn * 64 + j * 16 + lr];
#pragma unroll
    for (int i = 0; i < 4; ++i)
#pragma unroll
        for (int r = 0; r < 4; ++r) {
            int row = rowBase + wm * 64 + i * 16 + quad * 4 + r;   // m = D row (quad*4+reg)
#pragma unroll
            for (int j = 0; j < 4; ++j) {
                int col = colBase + wn * 64 + j * 16 + lr;          // n = D col (lane&15)
                C[(size_t)row * Ncols + col] = acc[i][j][r] + bj[j];
            }
        }
}

// One block per 4 queries. Phase A (256 threads x 2 items): coords + softmax
// for (q4, h, l, p). Phase B: thread = (q4, h, c4) handles 4 channels via float4.
// `sampled` may alias `off`: each block reads only its own 4 off-rows in phase A,
// syncs, then writes the same 4 rows in phase B. No cross-block sharing.
__global__ __launch_bounds__(256) void sample_kernel(
    const float* __restrict__ refp,            // (N, Lq, L, 2)
    const float* __restrict__ off,             // (N*Lq, 256)
    const float* __restrict__ attn,            // (N*Lq, 128)
    const float* __restrict__ value,           // (N, Lin, 256) d = h*32+c
    const int* __restrict__ shapes,            // (L, 2) [H, W]
    const int* __restrict__ starts,            // (L,)
    float* __restrict__ sampled)               // (N*Lq, 256)
{
    const int qBase = blockIdx.x * 4;
    const int t = threadIdx.x;

    __shared__ float sx[512], sy[512], sw[512];
    __shared__ int sH[NLV], sW4[NLV], sS[NLV];

    if (t < NLV) {
        sH[t] = shapes[2 * t];
        sW4[t] = shapes[2 * t + 1];
        sS[t] = starts[t];
    }

#pragma unroll
    for (int it = 0; it < 2; ++it) {
        const int i = t + it * 256;                   // item 0..511
        const int q4 = i >> 7, hlp = i & 127;
        const int h = hlp >> 4, lp = hlp & 15, l = lp >> 2, p = lp & 3;
        const int q = qBase + q4;
        const float Wl = (float)shapes[2 * l + 1];
        const float Hl = (float)shapes[2 * l];
        const float rx = refp[((size_t)q * NLV + l) * 2 + 0];
        const float ry = refp[((size_t)q * NLV + l) * 2 + 1];
        const int oidx = ((h * NLV + l) * NPT + p) * 2;
        const float ox = off[(size_t)q * DIM + oidx];
        const float oy = off[(size_t)q * DIM + oidx + 1];
        const float x = (rx + ox / Wl) * Wl - 0.5f;
        const float y = (ry + oy / Hl) * Hl - 0.5f;

        float logit = attn[(size_t)q * 128 + h * 16 + lp];
        float m = logit;
#pragma unroll
        for (int s = 8; s >= 1; s >>= 1) m = fmaxf(m, __shfl_xor(m, s, 16));
        float e = __expf(logit - m);
        float ssum = e;
#pragma unroll
        for (int s = 8; s >= 1; s >>= 1) ssum += __shfl_xor(ssum, s, 16);
        sx[i] = x;
        sy[i] = y;
        sw[i] = e / ssum;
    }
    __syncthreads();

    const int q4 = t >> 6, r = t & 63;
    const int h = r >> 3, c4 = (r & 7) * 4;
    const int q = qBase + q4;
    const int n = q / NQ;
    const float* vbase = value + (size_t)n * NQ * DIM + h * CHN + c4;

    f32x4 acc;
    acc[0] = acc[1] = acc[2] = acc[3] = 0.f;
#pragma unroll
    for (int l = 0; l < NLV; ++l) {
        const int Wl = sW4[l], Hl = sH[l];
        const float* vb = vbase + (size_t)sS[l] * DIM;
#pragma unroll
        for (int p = 0; p < NPT; ++p) {
            const int li = (q4 << 7) + (h << 4) + l * NPT + p;
            const float x = sx[li], y = sy[li], w = sw[li];
            const float xf = floorf(x), yf = floorf(y);
            const int ix = (int)xf, iy = (int)yf;
            const float wx = x - xf, wy = y - yf;
            const int ix1 = ix + 1, iy1 = iy + 1;
            const bool bx0 = (ix >= 0) & (ix < Wl);
            const bool bx1 = (ix1 >= 0) & (ix1 < Wl);
            const bool by0 = (iy >= 0) & (iy < Hl);
            const bool by1 = (iy1 >= 0) & (iy1 < Hl);
            const int cx0 = min(max(ix, 0), Wl - 1), cx1 = min(max(ix1, 0), Wl - 1);
            const int cy0 = min(max(iy, 0), Hl - 1), cy1 = min(max(iy1, 0), Hl - 1);
            const float w00 = (bx0 && by0) ? w * (1.f - wx) * (1.f - wy) : 0.f;
            const float w10 = (bx1 && by0) ? w * wx * (1.f - wy) : 0.f;
            const float w01 = (bx0 && by1) ? w * (1.f - wx) * wy : 0.f;
            const float w11 = (bx1 && by1) ? w * wx * wy : 0.f;
            const f32x4 v00 = *(const f32x4*)(vb + (size_t)(cy0 * Wl + cx0) * DIM);
            const f32x4 v10 = *(const f32x4*)(vb + (size_t)(cy0 * Wl + cx1) * DIM);
            const f32x4 v01 = *(const f32x4*)(vb + (size_t)(cy1 * Wl + cx0) * DIM);
            const f32x4 v11 = *(const f32x4*)(vb + (size_t)(cy1 * Wl + cx1) * DIM);
            acc += v00 * w00 + v10 * w10 + v01 * w01 + v11 * w11;
        }
    }
    *(f32x4*)(sampled + (size_t)q * DIM + h * CHN + c4) = acc;
}

extern "C" void kernel_launch(void* const* d_in, const int* in_sizes, int n_in,
                              void* d_out, int out_size, void* d_ws, size_t ws_size,
                              hipStream_t stream) {
    const float* query  = (const float*)d_in[0];
    const float* refp   = (const float*)d_in[1];
    const float* inputf = (const float*)d_in[2];
    const int* shapes   = (const int*)d_in[3];
    const int* starts   = (const int*)d_in[4];
    const float* W_off  = (const float*)d_in[5];
    const float* b_off  = (const float*)d_in[6];
    const float* W_attn = (const float*)d_in[7];
    const float* b_attn = (const float*)d_in[8];
    const float* W_val  = (const float*)d_in[9];
    const float* b_val  = (const float*)d_in[10];
    const float* W_out  = (const float*)d_in[11];
    const float* b_out  = (const float*)d_in[12];
    float* out = (float*)d_out;

    float* ws = (float*)d_ws;
    float* v_val  = ws;                              // MTOT*256
    float* v_off  = v_val + (size_t)MTOT * DIM;      // MTOT*256
    float* v_attn = v_off + (size_t)MTOT * DIM;      // MTOT*128
    float* v_samp = v_off;                           // aliases v_off (safe, see kernel)

    dim3 blk(256);
    gemm_mfma<<<dim3(MTOT / 128, 2), blk, 0, stream>>>(inputf, W_val, b_val, v_val, 256);
    gemm_mfma<<<dim3(MTOT / 128, 2), blk, 0, stream>>>(query, W_off, b_off, v_off, 256);
    gemm_mfma<<<dim3(MTOT / 128, 1), blk, 0, stream>>>(query, W_attn, b_attn, v_attn, 128);
    sample_kernel<<<dim3(MTOT / 4), blk, 0, stream>>>(refp, v_off, v_attn, v_val,
                                                      shapes, starts, v_samp);
    gemm_mfma<<<dim3(MTOT / 128, 2), blk, 0, stream>>>(v_samp, W_out, b_out, out, 256);
}

// Round 4
// 291.957 us; speedup vs baseline: 3.3814x; 1.2299x over previous
//
#include <hip/hip_runtime.h>
#include <hip/hip_bf16.h>

// Problem constants (fixed by setup_inputs)
#define NQ   5440
#define NB   8
#define DIM  256
#define NH   8
#define CHN  32
#define NLV  4
#define NPT  4
#define MTOT (NB * NQ)   // 43520

typedef __attribute__((ext_vector_type(8))) short s16x8;   // 8 bf16 in 4 VGPRs
typedef __attribute__((ext_vector_type(4))) short s16x4;   // 4 bf16
typedef __attribute__((ext_vector_type(4))) float f32x4;
typedef unsigned short ushort_t;

// bf16 weight-buffer segment offsets (elements): [W_val | W_off | W_attn | W_out]
#define WVAL 0
#define WOFF 65536
#define WATT 131072
#define WOUT 163840
#define WTOT 229376

__device__ __forceinline__ short f2bf(float x) {
    union { __hip_bfloat16 b; short s; } u;
    u.b = __float2bfloat16(x);
    return u.s;
}

// one-time fp32 -> bf16 conversion of all weight matrices into one buffer
__global__ __launch_bounds__(256) void cvt_weights(const float* __restrict__ wv,
                                                   const float* __restrict__ wo,
                                                   const float* __restrict__ wa,
                                                   const float* __restrict__ wu,
                                                   ushort_t* __restrict__ wb) {
    int i = (blockIdx.x * 256 + threadIdx.x) * 4;
    if (i >= WTOT) return;
    const float* src;
    int off;
    if (i < WOFF)       { src = wv; off = WVAL; }
    else if (i < WATT)  { src = wo; off = WOFF; }
    else if (i < WOUT)  { src = wa; off = WATT; }
    else                { src = wu; off = WOUT; }
    f32x4 v = *(const f32x4*)(src + (i - off));
    s16x4 b;
#pragma unroll
    for (int e = 0; e < 4; ++e) b[e] = f2bf(v[e]);
    *(s16x4*)(wb + i) = b;
}

#define LDSK 72   // bf16 elems per LDS row: 64 + 8 pad (144B stride, 16B aligned)

__device__ __forceinline__ s16x8 load8(const float* p) {
    f32x4 a0 = *(const f32x4*)p, a1 = *(const f32x4*)(p + 4);
    s16x8 v;
#pragma unroll
    for (int e = 0; e < 4; ++e) { v[e] = f2bf(a0[e]); v[e + 4] = f2bf(a1[e]); }
    return v;
}
__device__ __forceinline__ s16x8 load8(const ushort_t* p) { return *(const s16x8*)p; }

__device__ __forceinline__ void stC(float* p, float v) { *p = v; }
__device__ __forceinline__ void stC(ushort_t* p, float v) { *(short*)p = f2bf(v); }

// C[m, jloc] = sum_k A[rowBase+m, k] * Wt[jloc, k] + biasT[jloc]
// Wt/biasT/Ct pre-offset to this block's 128-column tile. 128x128 tile, BK=64,
// 256 threads (2x2 waves), 4x4 16x16x32 bf16 MFMA frags per wave.
template <typename AT, typename CT>
__device__ __forceinline__ void gemm_core(const AT* __restrict__ A,
                                          const ushort_t* __restrict__ Wt,
                                          const float* __restrict__ biasT,
                                          CT* __restrict__ Ct, int ldC, int rowBase) {
    __shared__ short As[128 * LDSK];
    __shared__ short Ws[128 * LDSK];

    const int t = threadIdx.x;
    const int lane = t & 63, wave = t >> 6;
    const int wm = wave >> 1, wn = wave & 1;
    const int lr = lane & 15, quad = lane >> 4;

    f32x4 acc[4][4];
#pragma unroll
    for (int i = 0; i < 4; ++i)
#pragma unroll
        for (int j = 0; j < 4; ++j)
#pragma unroll
            for (int r = 0; r < 4; ++r) acc[i][j][r] = 0.f;

    for (int k0 = 0; k0 < 256; k0 += 64) {
#pragma unroll
        for (int i = 0; i < 4; ++i) {
            int c = t + i * 256;            // 0..1023 chunk id (8 elems each)
            int r = c >> 3, kc = (c & 7) * 8;
            *(s16x8*)&As[r * LDSK + kc] = load8(A + (size_t)(rowBase + r) * DIM + k0 + kc);
            *(s16x8*)&Ws[r * LDSK + kc] = load8(Wt + (size_t)r * DIM + k0 + kc);
        }
        __syncthreads();
#pragma unroll
        for (int kk = 0; kk < 64; kk += 32) {
            s16x8 afr[4], wfr[4];
#pragma unroll
            for (int i = 0; i < 4; ++i)
                afr[i] = *(const s16x8*)&As[(wm * 64 + i * 16 + lr) * LDSK + kk + quad * 8];
#pragma unroll
            for (int j = 0; j < 4; ++j)
                wfr[j] = *(const s16x8*)&Ws[(wn * 64 + j * 16 + lr) * LDSK + kk + quad * 8];
#pragma unroll
            for (int i = 0; i < 4; ++i)
#pragma unroll
                for (int j = 0; j < 4; ++j)
                    acc[i][j] = __builtin_amdgcn_mfma_f32_16x16x32_bf16(
                        afr[i], wfr[j], acc[i][j], 0, 0, 0);
        }
        __syncthreads();
    }

    float bj[4];
#pragma unroll
    for (int j = 0; j < 4; ++j) bj[j] = biasT[wn * 64 + j * 16 + lr];
#pragma unroll
    for (int i = 0; i < 4; ++i)
#pragma unroll
        for (int r = 0; r < 4; ++r) {
            int row = rowBase + wm * 64 + i * 16 + quad * 4 + r;   // D row = quad*4+reg
#pragma unroll
            for (int j = 0; j < 4; ++j) {
                int col = wn * 64 + j * 16 + lr;                    // D col = lane&15
                stC(&Ct[(size_t)row * ldC + col], acc[i][j][r] + bj[j]);
            }
        }
}

__global__ __launch_bounds__(256) void gemm_val(const float* __restrict__ A,
                                                const ushort_t* __restrict__ wb,
                                                const float* __restrict__ bias,
                                                ushort_t* __restrict__ C) {
    gemm_core<float, ushort_t>(A, wb + WVAL + (size_t)blockIdx.y * 128 * DIM,
                               bias + blockIdx.y * 128, C + blockIdx.y * 128, DIM,
                               blockIdx.x * 128);
}

__global__ __launch_bounds__(256) void gemm_qkv(const float* __restrict__ A,
                                                const ushort_t* __restrict__ wb,
                                                const float* __restrict__ b_off,
                                                const float* __restrict__ b_attn,
                                                float* __restrict__ v_off,
                                                float* __restrict__ v_attn) {
    if (blockIdx.y < 2)
        gemm_core<float, float>(A, wb + WOFF + (size_t)blockIdx.y * 128 * DIM,
                                b_off + blockIdx.y * 128, v_off + blockIdx.y * 128, DIM,
                                blockIdx.x * 128);
    else
        gemm_core<float, float>(A, wb + WATT, b_attn, v_attn, 128, blockIdx.x * 128);
}

__global__ __launch_bounds__(256) void gemm_out(const ushort_t* __restrict__ A,
                                                const ushort_t* __restrict__ wb,
                                                const float* __restrict__ bias,
                                                float* __restrict__ C) {
    gemm_core<ushort_t, float>(A, wb + WOUT + (size_t)blockIdx.y * 128 * DIM,
                               bias + blockIdx.y * 128, C + blockIdx.y * 128, DIM,
                               blockIdx.x * 128);
}

__device__ __forceinline__ f32x4 bf4(uint2 u) {
    f32x4 r;
    r[0] = __uint_as_float(u.x << 16);
    r[1] = __uint_as_float(u.x & 0xffff0000u);
    r[2] = __uint_as_float(u.y << 16);
    r[3] = __uint_as_float(u.y & 0xffff0000u);
    return r;
}

// One block per 4 queries.
// Phase A (256 threads x 2 items = 512 = q4*h*l*p): coords + softmax + corner
//   indices/weights -> LDS. Slot layout q4*128 + lp*8 + h: phase B's 8 heads
//   read 8 consecutive 16B slots (conflict-free), 8 lanes/head broadcast.
// Phase B: thread = (q4, h, c4); 4 bf16 channels per corner via uint2 loads.
__global__ __launch_bounds__(256) void sample_kernel(
    const float* __restrict__ refp,            // (N, Lq, L, 2)
    const float* __restrict__ off,             // (N*Lq, 256)
    const float* __restrict__ attn,            // (N*Lq, 128)
    const ushort_t* __restrict__ valb,         // (N, Lin, 256) bf16, d = h*32+c
    const int* __restrict__ shapes,            // (L, 2) [H, W]
    const int* __restrict__ starts,            // (L,)
    ushort_t* __restrict__ sampb)              // (N*Lq, 256) bf16
{
    const int qBase = blockIdx.x * 4;
    const int t = threadIdx.x;

    __shared__ __align__(16) int   sidx[512][4];
    __shared__ __align__(16) float sww[512][4];

#pragma unroll
    for (int it = 0; it < 2; ++it) {
        const int i = t + it * 256;
        const int q4 = i >> 7, hlp = i & 127;
        const int h = hlp >> 4, lp = hlp & 15, l = lp >> 2, p = lp & 3;
        const int q = qBase + q4;
        const int Wl = shapes[2 * l + 1], Hl = shapes[2 * l];
        const float Wf = (float)Wl, Hf = (float)Hl;
        const float rx = refp[((size_t)q * NLV + l) * 2 + 0];
        const float ry = refp[((size_t)q * NLV + l) * 2 + 1];
        const int oidx = ((h * NLV + l) * NPT + p) * 2;
        const float ox = off[(size_t)q * DIM + oidx];
        const float oy = off[(size_t)q * DIM + oidx + 1];
        const float x = (rx + ox / Wf) * Wf - 0.5f;
        const float y = (ry + oy / Hf) * Hf - 0.5f;

        float logit = attn[(size_t)q * 128 + h * 16 + lp];
        float m = logit;
#pragma unroll
        for (int s = 8; s >= 1; s >>= 1) m = fmaxf(m, __shfl_xor(m, s, 16));
        float e = __expf(logit - m);
        float ss = e;
#pragma unroll
        for (int s = 8; s >= 1; s >>= 1) ss += __shfl_xor(ss, s, 16);
        const float aw = e / ss;

        const float xf = floorf(x), yf = floorf(y);
        const int ix = (int)xf, iy = (int)yf;
        const float wx = x - xf, wy = y - yf;
        const int ix1 = ix + 1, iy1 = iy + 1;
        const bool bx0 = (ix >= 0) & (ix < Wl);
        const bool bx1 = (ix1 >= 0) & (ix1 < Wl);
        const bool by0 = (iy >= 0) & (iy < Hl);
        const bool by1 = (iy1 >= 0) & (iy1 < Hl);
        const int cx0 = min(max(ix, 0), Wl - 1), cx1 = min(max(ix1, 0), Wl - 1);
        const int cy0 = min(max(iy, 0), Hl - 1), cy1 = min(max(iy1, 0), Hl - 1);
        const int base = starts[l];
        const int slot = (q4 << 7) + (lp << 3) + h;
        sidx[slot][0] = base + cy0 * Wl + cx0;
        sidx[slot][1] = base + cy0 * Wl + cx1;
        sidx[slot][2] = base + cy1 * Wl + cx0;
        sidx[slot][3] = base + cy1 * Wl + cx1;
        sww[slot][0] = (bx0 && by0) ? aw * (1.f - wx) * (1.f - wy) : 0.f;
        sww[slot][1] = (bx1 && by0) ? aw * wx * (1.f - wy) : 0.f;
        sww[slot][2] = (bx0 && by1) ? aw * (1.f - wx) * wy : 0.f;
        sww[slot][3] = (bx1 && by1) ? aw * wx * wy : 0.f;
    }
    __syncthreads();

    const int q4 = t >> 6, r = t & 63;
    const int h = r >> 3, c4 = (r & 7) * 4;
    const int q = qBase + q4;
    const int n = q / NQ;
    const ushort_t* vb = valb + (size_t)n * NQ * DIM + h * CHN + c4;

    f32x4 acc;
    acc[0] = acc[1] = acc[2] = acc[3] = 0.f;
#pragma unroll
    for (int lp = 0; lp < 16; ++lp) {
        const int slot = (q4 << 7) + (lp << 3) + h;
        const int4 id = *(const int4*)sidx[slot];
        const f32x4 w = *(const f32x4*)sww[slot];
        const uint2 u0 = *(const uint2*)(vb + (size_t)id.x * DIM);
        const uint2 u1 = *(const uint2*)(vb + (size_t)id.y * DIM);
        const uint2 u2 = *(const uint2*)(vb + (size_t)id.z * DIM);
        const uint2 u3 = *(const uint2*)(vb + (size_t)id.w * DIM);
        acc += bf4(u0) * w[0] + bf4(u1) * w[1] + bf4(u2) * w[2] + bf4(u3) * w[3];
    }
    s16x4 o;
#pragma unroll
    for (int e = 0; e < 4; ++e) o[e] = f2bf(acc[e]);
    *(s16x4*)(sampb + (size_t)q * DIM + h * CHN + c4) = o;
}

extern "C" void kernel_launch(void* const* d_in, const int* in_sizes, int n_in,
                              void* d_out, int out_size, void* d_ws, size_t ws_size,
                              hipStream_t stream) {
    const float* query  = (const float*)d_in[0];
    const float* refp   = (const float*)d_in[1];
    const float* inputf = (const float*)d_in[2];
    const int* shapes   = (const int*)d_in[3];
    const int* starts   = (const int*)d_in[4];
    const float* W_off  = (const float*)d_in[5];
    const float* b_off  = (const float*)d_in[6];
    const float* W_attn = (const float*)d_in[7];
    const float* b_attn = (const float*)d_in[8];
    const float* W_val  = (const float*)d_in[9];
    const float* b_val  = (const float*)d_in[10];
    const float* W_out  = (const float*)d_in[11];
    const float* b_out  = (const float*)d_in[12];
    float* out = (float*)d_out;

    // workspace layout (bytes): wb | v_val(bf16) | v_off(f32) | v_attn(f32) | samp(bf16)
    char* ws = (char*)d_ws;
    ushort_t* wb     = (ushort_t*)ws;                                   // 0.46 MB
    ushort_t* v_val  = (ushort_t*)(ws + 512 * 1024);                    // 22.3 MB
    float*    v_off  = (float*)(ws + 512 * 1024 + (size_t)MTOT * DIM * 2);   // 44.5 MB
    float*    v_attn = (float*)((char*)v_off + (size_t)MTOT * DIM * 4);      // 22.3 MB
    ushort_t* sampb  = (ushort_t*)((char*)v_attn + (size_t)MTOT * 128 * 4);  // 22.3 MB

    dim3 blk(256);
    cvt_weights<<<dim3(WTOT / 1024), blk, 0, stream>>>(W_val, W_off, W_attn, W_out, wb);
    gemm_val<<<dim3(MTOT / 128, 2), blk, 0, stream>>>(inputf, wb, b_val, v_val);
    gemm_qkv<<<dim3(MTOT / 128, 3), blk, 0, stream>>>(query, wb, b_off, b_attn,
                                                      v_off, v_attn);
    sample_kernel<<<dim3(MTOT / 4), blk, 0, stream>>>(refp, v_off, v_attn, v_val,
                                                      shapes, starts, sampb);
    gemm_out<<<dim3(MTOT / 128, 2), blk, 0, stream>>>(sampb, wb, b_out, out);
}

// Round 5
// 279.538 us; speedup vs baseline: 3.5317x; 1.0444x over previous
//
#include <hip/hip_runtime.h>
#include <hip/hip_bf16.h>

// Problem constants (fixed by setup_inputs)
#define NQ   5440
#define NB   8
#define DIM  256
#define NH   8
#define CHN  32
#define NLV  4
#define NPT  4
#define MTOT (NB * NQ)   // 43520

typedef __attribute__((ext_vector_type(8))) short s16x8;   // 8 bf16 in 4 VGPRs
typedef __attribute__((ext_vector_type(4))) short s16x4;   // 4 bf16
typedef __attribute__((ext_vector_type(4))) float f32x4;
typedef unsigned short ushort_t;

// bf16 weight-buffer segment offsets (elements): [W_val | W_off | W_attn | W_out]
#define WVAL 0
#define WOFF 65536
#define WATT 131072
#define WOUT 163840
#define WTOT 229376

__device__ __forceinline__ short f2bf(float x) {
    union { __hip_bfloat16 b; short s; } u;
    u.b = __float2bfloat16(x);
    return u.s;
}

// one-time fp32 -> bf16 conversion of all weight matrices into one buffer
__global__ __launch_bounds__(256) void cvt_weights(const float* __restrict__ wv,
                                                   const float* __restrict__ wo,
                                                   const float* __restrict__ wa,
                                                   const float* __restrict__ wu,
                                                   ushort_t* __restrict__ wb) {
    int i = (blockIdx.x * 256 + threadIdx.x) * 4;
    if (i >= WTOT) return;
    const float* src;
    int off;
    if (i < WOFF)       { src = wv; off = WVAL; }
    else if (i < WATT)  { src = wo; off = WOFF; }
    else if (i < WOUT)  { src = wa; off = WATT; }
    else                { src = wu; off = WOUT; }
    f32x4 v = *(const f32x4*)(src + (i - off));
    s16x4 b;
#pragma unroll
    for (int e = 0; e < 4; ++e) b[e] = f2bf(v[e]);
    *(s16x4*)(wb + i) = b;
}

#define LDSK 72   // bf16 elems per LDS row: 64 + 8 pad (144B stride, 16B aligned)

__device__ __forceinline__ void stC(float* p, float v) { *p = v; }
__device__ __forceinline__ void stC(ushort_t* p, float v) { *(short*)p = f2bf(v); }

// C[m, jloc] = sum_k A[rowBase+m, k] * Wt[jloc, k] + biasT[jloc]
// 128x128 tile, BK=64, 256 threads (2x2 waves), 4x4 16x16x32 bf16 MFMA frags.
// Software pipeline: next k-step's A/W tiles prefetched into registers so the
// 4 short-K global-load latencies overlap MFMA instead of serializing.
template <typename AT, typename CT>
__device__ __forceinline__ void gemm_core(const AT* __restrict__ A,
                                          const ushort_t* __restrict__ Wt,
                                          const float* __restrict__ biasT,
                                          CT* __restrict__ Ct, int ldC, int rowBase) {
    __shared__ short As[128 * LDSK];
    __shared__ short Ws[128 * LDSK];

    const int t = threadIdx.x;
    const int lane = t & 63, wave = t >> 6;
    const int wm = wave >> 1, wn = wave & 1;
    const int lr = lane & 15, quad = lane >> 4;

    f32x4 acc[4][4];
#pragma unroll
    for (int i = 0; i < 4; ++i)
#pragma unroll
        for (int j = 0; j < 4; ++j)
#pragma unroll
            for (int r = 0; r < 4; ++r) acc[i][j][r] = 0.f;

    f32x4 pf0[4], pf1[4];   // A prefetch (fp32 path)
    s16x8 pb[4];            // A prefetch (bf16 path)
    s16x8 pw[4];            // W prefetch

    // prologue: k-step 0 loads
#pragma unroll
    for (int i = 0; i < 4; ++i) {
        int c = t + i * 256, r = c >> 3, kc = (c & 7) * 8;
        const AT* pa = A + (size_t)(rowBase + r) * DIM + kc;
        if constexpr (sizeof(AT) == 4) {
            pf0[i] = *(const f32x4*)pa;
            pf1[i] = *(const f32x4*)(pa + 4);
        } else {
            pb[i] = *(const s16x8*)pa;
        }
        pw[i] = *(const s16x8*)(Wt + (size_t)r * DIM + kc);
    }

    for (int ks = 0; ks < 4; ++ks) {
        if (ks) __syncthreads();
        // write staged tiles to LDS (fp32->bf16 convert here, off the load path)
#pragma unroll
        for (int i = 0; i < 4; ++i) {
            int c = t + i * 256, r = c >> 3, kc = (c & 7) * 8;
            s16x8 av;
            if constexpr (sizeof(AT) == 4) {
#pragma unroll
                for (int e = 0; e < 4; ++e) {
                    av[e] = f2bf(pf0[i][e]);
                    av[e + 4] = f2bf(pf1[i][e]);
                }
            } else {
                av = pb[i];
            }
            *(s16x8*)&As[r * LDSK + kc] = av;
            *(s16x8*)&Ws[r * LDSK + kc] = pw[i];
        }
        // issue next k-step's loads (in flight across barrier + MFMA)
        if (ks < 3) {
            const int k0 = (ks + 1) * 64;
#pragma unroll
            for (int i = 0; i < 4; ++i) {
                int c = t + i * 256, r = c >> 3, kc = (c & 7) * 8;
                const AT* pa = A + (size_t)(rowBase + r) * DIM + k0 + kc;
                if constexpr (sizeof(AT) == 4) {
                    pf0[i] = *(const f32x4*)pa;
                    pf1[i] = *(const f32x4*)(pa + 4);
                } else {
                    pb[i] = *(const s16x8*)pa;
                }
                pw[i] = *(const s16x8*)(Wt + (size_t)r * DIM + k0 + kc);
            }
        }
        __syncthreads();
#pragma unroll
        for (int kk = 0; kk < 64; kk += 32) {
            s16x8 afr[4], wfr[4];
#pragma unroll
            for (int i = 0; i < 4; ++i)
                afr[i] = *(const s16x8*)&As[(wm * 64 + i * 16 + lr) * LDSK + kk + quad * 8];
#pragma unroll
            for (int j = 0; j < 4; ++j)
                wfr[j] = *(const s16x8*)&Ws[(wn * 64 + j * 16 + lr) * LDSK + kk + quad * 8];
#pragma unroll
            for (int i = 0; i < 4; ++i)
#pragma unroll
                for (int j = 0; j < 4; ++j)
                    acc[i][j] = __builtin_amdgcn_mfma_f32_16x16x32_bf16(
                        afr[i], wfr[j], acc[i][j], 0, 0, 0);
        }
    }

    float bj[4];
#pragma unroll
    for (int j = 0; j < 4; ++j) bj[j] = biasT[wn * 64 + j * 16 + lr];
#pragma unroll
    for (int i = 0; i < 4; ++i)
#pragma unroll
        for (int r = 0; r < 4; ++r) {
            int row = rowBase + wm * 64 + i * 16 + quad * 4 + r;   // D row = quad*4+reg
#pragma unroll
            for (int j = 0; j < 4; ++j) {
                int col = wn * 64 + j * 16 + lr;                    // D col = lane&15
                stC(&Ct[(size_t)row * ldC + col], acc[i][j][r] + bj[j]);
            }
        }
}

// val (2 col-tiles) + off (2) + attn (1) in one dispatch: grid (340, 5)
__global__ __launch_bounds__(256) void gemm_fused(const float* __restrict__ inputf,
                                                  const float* __restrict__ query,
                                                  const ushort_t* __restrict__ wb,
                                                  const float* __restrict__ b_val,
                                                  const float* __restrict__ b_off,
                                                  const float* __restrict__ b_attn,
                                                  ushort_t* __restrict__ v_val,
                                                  float* __restrict__ v_off,
                                                  float* __restrict__ v_attn) {
    const int gy = blockIdx.y;
    const int rowBase = blockIdx.x * 128;
    if (gy < 2)
        gemm_core<float, ushort_t>(inputf, wb + WVAL + (size_t)gy * 128 * DIM,
                                   b_val + gy * 128, v_val + gy * 128, DIM, rowBase);
    else if (gy < 4)
        gemm_core<float, float>(query, wb + WOFF + (size_t)(gy - 2) * 128 * DIM,
                                b_off + (gy - 2) * 128, v_off + (gy - 2) * 128, DIM,
                                rowBase);
    else
        gemm_core<float, float>(query, wb + WATT, b_attn, v_attn, 128, rowBase);
}

__global__ __launch_bounds__(256) void gemm_out(const ushort_t* __restrict__ A,
                                                const ushort_t* __restrict__ wb,
                                                const float* __restrict__ bias,
                                                float* __restrict__ C) {
    gemm_core<ushort_t, float>(A, wb + WOUT + (size_t)blockIdx.y * 128 * DIM,
                               bias + blockIdx.y * 128, C + blockIdx.y * 128, DIM,
                               blockIdx.x * 128);
}

// One block per 8 queries.
// Phase A (256 thr x 4 items = 1024 = q8*h*l*p): coords + softmax + corner BYTE
//   offsets/weights -> LDS at slot = item index (lane-consecutive 16B b128
//   writes: conflict-free).
// Phase B: thread = (q8, h, c8): 8 bf16 channels per corner via uint4 loads.
//   Read slot (q8,h,(j+h)&15): 8 distinct bank-groups, 2-way alias only (free).
__global__ __launch_bounds__(256) void sample_kernel(
    const float* __restrict__ refp,            // (N, Lq, L, 2)
    const float* __restrict__ off,             // (N*Lq, 256)
    const float* __restrict__ attn,            // (N*Lq, 128)
    const ushort_t* __restrict__ valb,         // (N, Lin, 256) bf16, d = h*32+c
    const int* __restrict__ shapes,            // (L, 2) [H, W]
    const int* __restrict__ starts,            // (L,)
    ushort_t* __restrict__ sampb)              // (N*Lq, 256) bf16
{
    const int qBase = blockIdx.x * 8;
    const int t = threadIdx.x;

    __shared__ __align__(16) int   sidx[1024][4];
    __shared__ __align__(16) float sww[1024][4];

#pragma unroll
    for (int it = 0; it < 4; ++it) {
        const int i = t + it * 256;
        const int q8 = i >> 7, hlp = i & 127;
        const int h = hlp >> 4, lp = hlp & 15, l = lp >> 2;
        const int q = qBase + q8;
        const int n = q / NQ;
        const int Wl = shapes[2 * l + 1], Hl = shapes[2 * l];
        const float Wf = (float)Wl, Hf = (float)Hl;
        const float2 rp = *(const float2*)(refp + ((size_t)q * NLV + l) * 2);
        const float2 oo = *(const float2*)(off + (size_t)q * DIM + h * 32 + lp * 2);
        const float x = (rp.x + oo.x / Wf) * Wf - 0.5f;
        const float y = (rp.y + oo.y / Hf) * Hf - 0.5f;

        float logit = attn[(size_t)q * 128 + h * 16 + lp];
        float m = logit;
#pragma unroll
        for (int s = 8; s >= 1; s >>= 1) m = fmaxf(m, __shfl_xor(m, s, 16));
        float e = __expf(logit - m);
        float ss = e;
#pragma unroll
        for (int s = 8; s >= 1; s >>= 1) ss += __shfl_xor(ss, s, 16);
        const float aw = e / ss;

        const float xf = floorf(x), yf = floorf(y);
        const int ix = (int)xf, iy = (int)yf;
        const float wx = x - xf, wy = y - yf;
        const int ix1 = ix + 1, iy1 = iy + 1;
        const bool bx0 = (ix >= 0) & (ix < Wl);
        const bool bx1 = (ix1 >= 0) & (ix1 < Wl);
        const bool by0 = (iy >= 0) & (iy < Hl);
        const bool by1 = (iy1 >= 0) & (iy1 < Hl);
        const int cx0 = min(max(ix, 0), Wl - 1), cx1 = min(max(ix1, 0), Wl - 1);
        const int cy0 = min(max(iy, 0), Hl - 1), cy1 = min(max(iy1, 0), Hl - 1);
        const int base = n * NQ + starts[l];
        int4 id;
        id.x = (base + cy0 * Wl + cx0) << 9;   // byte offset (row stride 512B)
        id.y = (base + cy0 * Wl + cx1) << 9;
        id.z = (base + cy1 * Wl + cx0) << 9;
        id.w = (base + cy1 * Wl + cx1) << 9;
        f32x4 w;
        w[0] = (bx0 && by0) ? aw * (1.f - wx) * (1.f - wy) : 0.f;
        w[1] = (bx1 && by0) ? aw * wx * (1.f - wy) : 0.f;
        w[2] = (bx0 && by1) ? aw * (1.f - wx) * wy : 0.f;
        w[3] = (bx1 && by1) ? aw * wx * wy : 0.f;
        *(int4*)sidx[i] = id;                   // lane-consecutive 16B: conflict-free
        *(f32x4*)sww[i] = w;
    }
    __syncthreads();

    const int q8 = t >> 5, r = t & 31;
    const int h = r >> 2, cg = r & 3;           // 8 channels per thread
    const int q = qBase + q8;
    const char* vb = (const char*)valb + h * 64 + cg * 16;

    f32x4 acc0, acc1;
    acc0[0] = acc0[1] = acc0[2] = acc0[3] = 0.f;
    acc1[0] = acc1[1] = acc1[2] = acc1[3] = 0.f;
#pragma unroll
    for (int j = 0; j < 16; ++j) {
        const int lp = (j + h) & 15;            // per-head rotation: 2-way max alias
        const int slot = (q8 << 7) + (h << 4) + lp;
        const int4 id = *(const int4*)sidx[slot];
        const f32x4 w = *(const f32x4*)sww[slot];
        const uint4 u0 = *(const uint4*)(vb + (size_t)(unsigned)id.x);
        const uint4 u1 = *(const uint4*)(vb + (size_t)(unsigned)id.y);
        const uint4 u2 = *(const uint4*)(vb + (size_t)(unsigned)id.z);
        const uint4 u3 = *(const uint4*)(vb + (size_t)(unsigned)id.w);
#define ACC8(u, wgt)                                                          \
        {                                                                     \
            f32x4 lo, hi;                                                     \
            lo[0] = __uint_as_float(u.x << 16);                               \
            lo[1] = __uint_as_float(u.x & 0xffff0000u);                       \
            lo[2] = __uint_as_float(u.y << 16);                               \
            lo[3] = __uint_as_float(u.y & 0xffff0000u);                       \
            hi[0] = __uint_as_float(u.z << 16);                               \
            hi[1] = __uint_as_float(u.z & 0xffff0000u);                       \
            hi[2] = __uint_as_float(u.w << 16);                               \
            hi[3] = __uint_as_float(u.w & 0xffff0000u);                       \
            acc0 += lo * (wgt);                                               \
            acc1 += hi * (wgt);                                               \
        }
        ACC8(u0, w[0]);
        ACC8(u1, w[1]);
        ACC8(u2, w[2]);
        ACC8(u3, w[3]);
#undef ACC8
    }
    s16x8 o;
#pragma unroll
    for (int e = 0; e < 4; ++e) {
        o[e] = f2bf(acc0[e]);
        o[e + 4] = f2bf(acc1[e]);
    }
    *(s16x8*)(sampb + (size_t)q * DIM + h * CHN + cg * 8) = o;
}

extern "C" void kernel_launch(void* const* d_in, const int* in_sizes, int n_in,
                              void* d_out, int out_size, void* d_ws, size_t ws_size,
                              hipStream_t stream) {
    const float* query  = (const float*)d_in[0];
    const float* refp   = (const float*)d_in[1];
    const float* inputf = (const float*)d_in[2];
    const int* shapes   = (const int*)d_in[3];
    const int* starts   = (const int*)d_in[4];
    const float* W_off  = (const float*)d_in[5];
    const float* b_off  = (const float*)d_in[6];
    const float* W_attn = (const float*)d_in[7];
    const float* b_attn = (const float*)d_in[8];
    const float* W_val  = (const float*)d_in[9];
    const float* b_val  = (const float*)d_in[10];
    const float* W_out  = (const float*)d_in[11];
    const float* b_out  = (const float*)d_in[12];
    float* out = (float*)d_out;

    // workspace layout (bytes): wb | v_val(bf16) | v_off(f32) | v_attn(f32) | samp(bf16)
    char* ws = (char*)d_ws;
    ushort_t* wb     = (ushort_t*)ws;                                   // 0.46 MB
    ushort_t* v_val  = (ushort_t*)(ws + 512 * 1024);                    // 22.3 MB
    float*    v_off  = (float*)(ws + 512 * 1024 + (size_t)MTOT * DIM * 2);   // 44.5 MB
    float*    v_attn = (float*)((char*)v_off + (size_t)MTOT * DIM * 4);      // 22.3 MB
    ushort_t* sampb  = (ushort_t*)((char*)v_attn + (size_t)MTOT * 128 * 4);  // 22.3 MB

    dim3 blk(256);
    cvt_weights<<<dim3(WTOT / 1024), blk, 0, stream>>>(W_val, W_off, W_attn, W_out, wb);
    gemm_fused<<<dim3(MTOT / 128, 5), blk, 0, stream>>>(inputf, query, wb, b_val,
                                                        b_off, b_attn, v_val, v_off,
                                                        v_attn);
    sample_kernel<<<dim3(MTOT / 8), blk, 0, stream>>>(refp, v_off, v_attn, v_val,
                                                      shapes, starts, sampb);
    gemm_out<<<dim3(MTOT / 128, 2), blk, 0, stream>>>(sampb, wb, b_out, out);
}

// Round 6
// 277.970 us; speedup vs baseline: 3.5516x; 1.0056x over previous
//
#include <hip/hip_runtime.h>
#include <hip/hip_bf16.h>
#include <hip/hip_fp16.h>

// Problem constants (fixed by setup_inputs)
#define NQ   5440
#define NB   8
#define DIM  256
#define NH   8
#define CHN  32
#define NLV  4
#define NPT  4
#define MTOT (NB * NQ)   // 43520

typedef __attribute__((ext_vector_type(8))) short s16x8;   // 8 bf16 (4 VGPRs)
typedef __attribute__((ext_vector_type(4))) short s16x4;
typedef __attribute__((ext_vector_type(4))) float f32x4;
typedef unsigned short ushort_t;

// bf16 weight-buffer segment offsets (elements): [W_val | W_off | W_attn | W_out]
#define WVAL 0
#define WOFF 65536
#define WATT 131072
#define WOUT 163840
#define WTOT 229376

__device__ __forceinline__ short f2bf(float x) {
    union { __hip_bfloat16 b; short s; } u;
    u.b = __float2bfloat16(x);
    return u.s;
}

// async 16B global->LDS copy; LDS dst = wave-uniform base + lane*16
__device__ __forceinline__ void gload_lds16(const void* g, void* l) {
    __builtin_amdgcn_global_load_lds(
        (const __attribute__((address_space(1))) unsigned int*)g,
        (__attribute__((address_space(3))) unsigned int*)l, 16, 0, 0);
}

__device__ __forceinline__ void cvt8b(const float* s, ushort_t* d) {
    f32x4 a = *(const f32x4*)s, b = *(const f32x4*)(s + 4);
    s16x8 v;
#pragma unroll
    for (int e = 0; e < 4; ++e) { v[e] = f2bf(a[e]); v[e + 4] = f2bf(b[e]); }
    *(s16x8*)d = v;
}

// One pass: inputf -> bf16, query -> bf16, 4 weight mats -> bf16
__global__ __launch_bounds__(256) void cvt_all(const float* __restrict__ inputf,
                                               const float* __restrict__ query,
                                               const float* __restrict__ wv,
                                               const float* __restrict__ wo,
                                               const float* __restrict__ wa,
                                               const float* __restrict__ wu,
                                               ushort_t* __restrict__ binf,
                                               ushort_t* __restrict__ bq,
                                               ushort_t* __restrict__ wb) {
    const int i = (blockIdx.x * 256 + threadIdx.x) * 8;
    if (blockIdx.y == 0) {
        cvt8b(inputf + i, binf + i);
    } else if (blockIdx.y == 1) {
        cvt8b(query + i, bq + i);
    } else {
        if (i >= WTOT) return;
        const float* src;
        int off;
        if (i < WOFF)      { src = wv; off = WVAL; }
        else if (i < WATT) { src = wo; off = WOFF; }
        else if (i < WOUT) { src = wa; off = WATT; }
        else               { src = wu; off = WOUT; }
        cvt8b(src + (i - off), wb + i);
    }
}

__device__ __forceinline__ void stC(float* p, float v) { *p = v; }
__device__ __forceinline__ void stC(__half* p, float v) { *p = __float2half(v); }

// C[m, jloc] = sum_k A[rowBase+m, k] * Wt[jloc, k] + biasT[jloc]
// 128x128 tile, BK=64, 256 threads (2x2 waves), 4x4 16x16x32 bf16 MFMA frags.
// Staging via global_load_lds (16B), XOR-swizzled LDS chunks:
//   row r (128B = 8 chunks of 16B); logical k-group g stored at slot (g+r)&7.
//   Staging lane->chunk is identity (HW: base+lane*16); source addr computes
//   the inverse swizzle. Fragment ds_read_b128: 16 rows -> 8 bank-groups x2
//   (2-way alias = free).
template <typename CT>
__device__ __forceinline__ void gemm_core(const ushort_t* __restrict__ A,
                                          const ushort_t* __restrict__ Wt,
                                          const float* __restrict__ biasT,
                                          CT* __restrict__ Ct, int ldC, int rowBase) {
    __shared__ ushort_t As[128 * 64];   // 16 KB
    __shared__ ushort_t Ws[128 * 64];   // 16 KB

    const int t = threadIdx.x;
    const int lane = t & 63, w = t >> 6;
    const int wm = w >> 1, wn = w & 1;
    const int lr = lane & 15, quad = lane >> 4;

    f32x4 acc[4][4];
#pragma unroll
    for (int i = 0; i < 4; ++i)
#pragma unroll
        for (int j = 0; j < 4; ++j)
#pragma unroll
            for (int r = 0; r < 4; ++r) acc[i][j][r] = 0.f;

    for (int ks = 0; ks < 4; ++ks) {
        if (ks) __syncthreads();
#pragma unroll
        for (int i = 0; i < 4; ++i) {
            const int c = t + i * 256;          // chunk id 0..1023
            const int r = c >> 3, s = c & 7;
            const int g = (s - r) & 7;          // inverse swizzle
            const int ke = ks * 64 + g * 8;     // element k-offset
            gload_lds16(A + (size_t)(rowBase + r) * DIM + ke,
                        &As[(size_t)(i * 256 + w * 64) * 8]);
            gload_lds16(Wt + (size_t)r * DIM + ke,
                        &Ws[(size_t)(i * 256 + w * 64) * 8]);
        }
        __syncthreads();                        // drains vmcnt(0) + barrier
#pragma unroll
        for (int kk = 0; kk < 64; kk += 32) {
            s16x8 afr[4], wfr[4];
            const int G = (kk >> 3) + quad;
#pragma unroll
            for (int i = 0; i < 4; ++i) {
                const int R = wm * 64 + i * 16 + lr;
                afr[i] = *(const s16x8*)&As[(R * 8 + ((G + R) & 7)) * 8];
            }
#pragma unroll
            for (int j = 0; j < 4; ++j) {
                const int R = wn * 64 + j * 16 + lr;
                wfr[j] = *(const s16x8*)&Ws[(R * 8 + ((G + R) & 7)) * 8];
            }
#pragma unroll
            for (int i = 0; i < 4; ++i)
#pragma unroll
                for (int j = 0; j < 4; ++j)
                    acc[i][j] = __builtin_amdgcn_mfma_f32_16x16x32_bf16(
                        afr[i], wfr[j], acc[i][j], 0, 0, 0);
        }
    }

    float bj[4];
#pragma unroll
    for (int j = 0; j < 4; ++j) bj[j] = biasT[wn * 64 + j * 16 + lr];
#pragma unroll
    for (int i = 0; i < 4; ++i)
#pragma unroll
        for (int r = 0; r < 4; ++r) {
            int row = rowBase + wm * 64 + i * 16 + quad * 4 + r;   // D row
#pragma unroll
            for (int j = 0; j < 4; ++j) {
                int col = wn * 64 + j * 16 + lr;                    // D col
                stC(&Ct[(size_t)row * ldC + col], acc[i][j][r] + bj[j]);
            }
        }
}

// val (2 col-tiles, f16 out) + off (2, f32) + attn (1, f32): grid (340, 5)
__global__ __launch_bounds__(256) void gemm_fused(const ushort_t* __restrict__ binf,
                                                  const ushort_t* __restrict__ bq,
                                                  const ushort_t* __restrict__ wb,
                                                  const float* __restrict__ b_val,
                                                  const float* __restrict__ b_off,
                                                  const float* __restrict__ b_attn,
                                                  __half* __restrict__ bval,
                                                  float* __restrict__ v_off,
                                                  float* __restrict__ v_attn) {
    const int gy = blockIdx.y;
    const int rowBase = blockIdx.x * 128;
    if (gy < 2)
        gemm_core<__half>(binf, wb + WVAL + (size_t)gy * 128 * DIM,
                          b_val + gy * 128, bval + gy * 128, DIM, rowBase);
    else if (gy < 4)
        gemm_core<float>(bq, wb + WOFF + (size_t)(gy - 2) * 128 * DIM,
                         b_off + (gy - 2) * 128, v_off + (gy - 2) * 128, DIM, rowBase);
    else
        gemm_core<float>(bq, wb + WATT, b_attn, v_attn, 128, rowBase);
}

__global__ __launch_bounds__(256) void gemm_out(const ushort_t* __restrict__ A,
                                                const ushort_t* __restrict__ wb,
                                                const float* __restrict__ bias,
                                                float* __restrict__ C) {
    gemm_core<float>(A, wb + WOUT + (size_t)blockIdx.y * 128 * DIM,
                     bias + blockIdx.y * 128, C + blockIdx.y * 128, DIM,
                     blockIdx.x * 128);
}

// One block per 4 queries, 128 threads.
// Phase A (128 thr x 4 items = 512 = q4*h*l*p): coords + softmax + corner BYTE
//   offsets + packed-half2 weights -> LDS at slot = item idx (16B b128 writes).
// Phase B: thread = (q4, h, cg): 8 f16 channels per corner via uint4 loads;
//   4 v_pk_fma_f16 per corner; f32 flush every 4 iterations.
__global__ __launch_bounds__(128) void sample_kernel(
    const float* __restrict__ refp,            // (N, Lq, L, 2)
    const float* __restrict__ off,             // (N*Lq, 256)
    const float* __restrict__ attn,            // (N*Lq, 128)
    const __half* __restrict__ bval,           // (N, Lin, 256) f16, d = h*32+c
    const int* __restrict__ shapes,            // (L, 2) [H, W]
    const int* __restrict__ starts,            // (L,)
    ushort_t* __restrict__ sampb)              // (N*Lq, 256) bf16
{
    const int qBase = blockIdx.x * 4;
    const int t = threadIdx.x;

    __shared__ __align__(16) int     sidx[512][4];   // 8 KB
    __shared__ __align__(16) __half2 sww[512][4];    // 8 KB

#pragma unroll
    for (int it = 0; it < 4; ++it) {
        const int i = t + it * 128;
        const int q4 = i >> 7, hlp = i & 127;
        const int h = hlp >> 4, lp = hlp & 15, l = lp >> 2;
        const int q = qBase + q4;
        const int n = q / NQ;
        const int Wl = shapes[2 * l + 1], Hl = shapes[2 * l];
        const float Wf = (float)Wl, Hf = (float)Hl;
        const float2 rp = *(const float2*)(refp + ((size_t)q * NLV + l) * 2);
        const float2 oo = *(const float2*)(off + (size_t)q * DIM + h * 32 + lp * 2);
        const float x = (rp.x + oo.x / Wf) * Wf - 0.5f;
        const float y = (rp.y + oo.y / Hf) * Hf - 0.5f;

        float logit = attn[(size_t)q * 128 + h * 16 + lp];
        float m = logit;
#pragma unroll
        for (int s = 8; s >= 1; s >>= 1) m = fmaxf(m, __shfl_xor(m, s, 16));
        float e = __expf(logit - m);
        float ss = e;
#pragma unroll
        for (int s = 8; s >= 1; s >>= 1) ss += __shfl_xor(ss, s, 16);
        const float aw = e / ss;

        const float xf = floorf(x), yf = floorf(y);
        const int ix = (int)xf, iy = (int)yf;
        const float wx = x - xf, wy = y - yf;
        const int ix1 = ix + 1, iy1 = iy + 1;
        const bool bx0 = (ix >= 0) & (ix < Wl);
        const bool bx1 = (ix1 >= 0) & (ix1 < Wl);
        const bool by0 = (iy >= 0) & (iy < Hl);
        const bool by1 = (iy1 >= 0) & (iy1 < Hl);
        const int cx0 = min(max(ix, 0), Wl - 1), cx1 = min(max(ix1, 0), Wl - 1);
        const int cy0 = min(max(iy, 0), Hl - 1), cy1 = min(max(iy1, 0), Hl - 1);
        const int base = n * NQ + starts[l];
        int4 id;
        id.x = (base + cy0 * Wl + cx0) << 9;   // byte offset (row stride 512B)
        id.y = (base + cy0 * Wl + cx1) << 9;
        id.z = (base + cy1 * Wl + cx0) << 9;
        id.w = (base + cy1 * Wl + cx1) << 9;
        __half2 wp[4];
        wp[0] = __float2half2_rn((bx0 && by0) ? aw * (1.f - wx) * (1.f - wy) : 0.f);
        wp[1] = __float2half2_rn((bx1 && by0) ? aw * wx * (1.f - wy) : 0.f);
        wp[2] = __float2half2_rn((bx0 && by1) ? aw * (1.f - wx) * wy : 0.f);
        wp[3] = __float2half2_rn((bx1 && by1) ? aw * wx * wy : 0.f);
        *(int4*)sidx[i] = id;
        *(uint4*)&sww[i][0] = *(uint4*)wp;
    }
    __syncthreads();

    const int q4 = t >> 5, r = t & 31;
    const int h = r >> 2, cg = r & 3;           // 8 channels per thread
    const int q = qBase + q4;
    const char* vb = (const char*)bval + h * 64 + cg * 16;

    __half2 acch[4];
    float accf[8];
#pragma unroll
    for (int e = 0; e < 4; ++e) acch[e] = __float2half2_rn(0.f);
#pragma unroll
    for (int e = 0; e < 8; ++e) accf[e] = 0.f;

#pragma unroll
    for (int j = 0; j < 16; ++j) {
        const int lp = (j + h) & 15;            // per-head rotation: 2-way max alias
        const int slot = (q4 << 7) + (h << 4) + lp;
        const int4 id = *(const int4*)sidx[slot];
        uint4 wu = *(const uint4*)&sww[slot][0];
        const __half2* wp = (const __half2*)&wu;
        int idc[4] = {id.x, id.y, id.z, id.w};
#pragma unroll
        for (int c = 0; c < 4; ++c) {
            const uint4 u = *(const uint4*)(vb + (size_t)(unsigned)idc[c]);
            const __half2* hv = (const __half2*)&u;
#pragma unroll
            for (int e = 0; e < 4; ++e) acch[e] = __hfma2(hv[e], wp[c], acch[e]);
        }
        if ((j & 3) == 3) {
#pragma unroll
            for (int e = 0; e < 4; ++e) {
                float2 f = __half22float2(acch[e]);
                accf[2 * e] += f.x;
                accf[2 * e + 1] += f.y;
                acch[e] = __float2half2_rn(0.f);
            }
        }
    }

    s16x8 o;
#pragma unroll
    for (int e = 0; e < 8; ++e) o[e] = f2bf(accf[e]);
    *(s16x8*)(sampb + (size_t)q * DIM + h * CHN + cg * 8) = o;
}

extern "C" void kernel_launch(void* const* d_in, const int* in_sizes, int n_in,
                              void* d_out, int out_size, void* d_ws, size_t ws_size,
                              hipStream_t stream) {
    const float* query  = (const float*)d_in[0];
    const float* refp   = (const float*)d_in[1];
    const float* inputf = (const float*)d_in[2];
    const int* shapes   = (const int*)d_in[3];
    const int* starts   = (const int*)d_in[4];
    const float* W_off  = (const float*)d_in[5];
    const float* b_off  = (const float*)d_in[6];
    const float* W_attn = (const float*)d_in[7];
    const float* b_attn = (const float*)d_in[8];
    const float* W_val  = (const float*)d_in[9];
    const float* b_val  = (const float*)d_in[10];
    const float* W_out  = (const float*)d_in[11];
    const float* b_out  = (const float*)d_in[12];
    float* out = (float*)d_out;

    // workspace (bytes): wb | binf | bq | bval(f16) | v_off(f32) | v_attn(f32)
    // sampb aliases binf (binf fully consumed by gemm_fused before sampler runs)
    const size_t AB = (size_t)MTOT * DIM * 2;   // 22,282,240
    char* ws = (char*)d_ws;
    ushort_t* wb    = (ushort_t*)ws;
    ushort_t* binf  = (ushort_t*)(ws + 512 * 1024);
    ushort_t* bq    = (ushort_t*)(ws + 512 * 1024 + AB);
    __half*   bval  = (__half*)(ws + 512 * 1024 + 2 * AB);
    float*    v_off = (float*)(ws + 512 * 1024 + 3 * AB);
    float*    v_attn= (float*)(ws + 512 * 1024 + 3 * AB + (size_t)MTOT * DIM * 4);
    ushort_t* sampb = binf;

    cvt_all<<<dim3(MTOT * DIM / 2048, 3), dim3(256), 0, stream>>>(
        inputf, query, W_val, W_off, W_attn, W_out, binf, bq, wb);
    gemm_fused<<<dim3(MTOT / 128, 5), dim3(256), 0, stream>>>(
        binf, bq, wb, b_val, b_off, b_attn, bval, v_off, v_attn);
    sample_kernel<<<dim3(MTOT / 4), dim3(128), 0, stream>>>(
        refp, v_off, v_attn, bval, shapes, starts, sampb);
    gemm_out<<<dim3(MTOT / 128, 2), dim3(256), 0, stream>>>(sampb, wb, b_out, out);
}

// Round 7
// 257.296 us; speedup vs baseline: 3.8369x; 1.0803x over previous
//
#include <hip/hip_runtime.h>
#include <hip/hip_bf16.h>
#include <hip/hip_fp16.h>

// Problem constants (fixed by setup_inputs)
#define NQ   5440
#define NB   8
#define DIM  256
#define NH   8
#define CHN  32
#define NLV  4
#define NPT  4
#define MTOT (NB * NQ)   // 43520

typedef __attribute__((ext_vector_type(8))) short s16x8;   // 8 x 16-bit (4 VGPRs)
typedef __attribute__((ext_vector_type(4))) float f32x4;
typedef unsigned short ushort_t;

// bf16 weight-buffer segment offsets (elements): [W_val | W_off | W_attn | W_out]
#define WVAL 0
#define WOFF 65536
#define WATT 131072
#define WOUT 163840
#define WTOT 229376

__device__ __forceinline__ short f2bf(float x) {
    union { __hip_bfloat16 b; short s; } u;
    u.b = __float2bfloat16(x);
    return u.s;
}

// async 16B global->LDS copy; LDS dst = wave-uniform base + lane*16
__device__ __forceinline__ void gload_lds16(const void* g, void* l) {
    __builtin_amdgcn_global_load_lds(
        (const __attribute__((address_space(1))) unsigned int*)g,
        (__attribute__((address_space(3))) unsigned int*)l, 16, 0, 0);
}

__device__ __forceinline__ void cvt8b(const float* s, ushort_t* d) {
    f32x4 a = *(const f32x4*)s, b = *(const f32x4*)(s + 4);
    s16x8 v;
#pragma unroll
    for (int e = 0; e < 4; ++e) { v[e] = f2bf(a[e]); v[e + 4] = f2bf(b[e]); }
    *(s16x8*)d = v;
}

// one-time fp32 -> bf16 of the 4 weight matrices (0.9 MB read, ~2 us)
__global__ __launch_bounds__(256) void cvt_weights(const float* __restrict__ wv,
                                                   const float* __restrict__ wo,
                                                   const float* __restrict__ wa,
                                                   const float* __restrict__ wu,
                                                   ushort_t* __restrict__ wb) {
    const int i = (blockIdx.x * 256 + threadIdx.x) * 8;
    if (i >= WTOT) return;
    const float* src;
    int off;
    if (i < WOFF)      { src = wv; off = WVAL; }
    else if (i < WATT) { src = wo; off = WOFF; }
    else if (i < WOUT) { src = wa; off = WATT; }
    else               { src = wu; off = WOUT; }
    cvt8b(src + (i - off), wb + i);
}

__device__ __forceinline__ void stC(float* p, float v) { *p = v; }
__device__ __forceinline__ void stC(__half* p, float v) { *p = __float2half(v); }
__device__ __forceinline__ void stC(ushort_t* p, float v) { *(short*)p = f2bf(v); }

// C[m, jloc] = sum_k A[rowBase+m, k] * Wt[jloc, k] + biasT[jloc]
// 128x128 tile, BK=64, 256 threads (2x2 waves), 4x4 16x16x32 bf16 MFMA frags.
// LDS layout XOR-swizzled in 16B chunks: row r's k-group g lives at slot
// (g+r)&7 (row = 128B = 8 chunks). Staging writes are lane-consecutive 16B
// (conflict-free); fragment ds_read_b128 hits 8 bank-groups, 2-way alias
// (free). A path: fp32 source, cvt fused into staging ds_write. bf16 source:
// async global_load_lds (identity lane->chunk placement, inverse-swizzled
// source address).
template <typename AT, typename CT>
__device__ __forceinline__ void gemm_core(const AT* __restrict__ A,
                                          const ushort_t* __restrict__ Wt,
                                          const float* __restrict__ biasT,
                                          CT* __restrict__ Ct, int ldC, int rowBase) {
    __shared__ ushort_t As[128 * 64];   // 16 KB
    __shared__ ushort_t Ws[128 * 64];   // 16 KB

    const int t = threadIdx.x;
    const int lane = t & 63, w = t >> 6;
    const int wm = w >> 1, wn = w & 1;
    const int lr = lane & 15, quad = lane >> 4;

    f32x4 acc[4][4];
#pragma unroll
    for (int i = 0; i < 4; ++i)
#pragma unroll
        for (int j = 0; j < 4; ++j)
#pragma unroll
            for (int r = 0; r < 4; ++r) acc[i][j][r] = 0.f;

    for (int ks = 0; ks < 4; ++ks) {
        if (ks) __syncthreads();
#pragma unroll
        for (int i = 0; i < 4; ++i) {
            const int c = t + i * 256;          // chunk id 0..1023
            const int r = c >> 3, s = c & 7;
            const int g = (s - r) & 7;          // inverse swizzle
            const int ke = ks * 64 + g * 8;     // element k-offset
            gload_lds16(Wt + (size_t)r * DIM + ke,
                        &Ws[(size_t)(i * 256 + w * 64) * 8]);
            if constexpr (sizeof(AT) == 2) {
                gload_lds16(A + (size_t)(rowBase + r) * DIM + ke,
                            &As[(size_t)(i * 256 + w * 64) * 8]);
            } else {
                const float* pa = (const float*)A + (size_t)(rowBase + r) * DIM + ke;
                f32x4 a0 = *(const f32x4*)pa, a1 = *(const f32x4*)(pa + 4);
                s16x8 av;
#pragma unroll
                for (int e = 0; e < 4; ++e) {
                    av[e] = f2bf(a0[e]);
                    av[e + 4] = f2bf(a1[e]);
                }
                *(s16x8*)&As[(size_t)c * 8] = av;   // slot == chunk id (identity)
            }
        }
        __syncthreads();                        // drains vm+lgkm, barrier
#pragma unroll
        for (int kk = 0; kk < 64; kk += 32) {
            s16x8 afr[4], wfr[4];
            const int G = (kk >> 3) + quad;
#pragma unroll
            for (int i = 0; i < 4; ++i) {
                const int R = wm * 64 + i * 16 + lr;
                afr[i] = *(const s16x8*)&As[(R * 8 + ((G + R) & 7)) * 8];
            }
#pragma unroll
            for (int j = 0; j < 4; ++j) {
                const int R = wn * 64 + j * 16 + lr;
                wfr[j] = *(const s16x8*)&Ws[(R * 8 + ((G + R) & 7)) * 8];
            }
#pragma unroll
            for (int i = 0; i < 4; ++i)
#pragma unroll
                for (int j = 0; j < 4; ++j)
                    acc[i][j] = __builtin_amdgcn_mfma_f32_16x16x32_bf16(
                        afr[i], wfr[j], acc[i][j], 0, 0, 0);
        }
    }

    float bj[4];
#pragma unroll
    for (int j = 0; j < 4; ++j) bj[j] = biasT[wn * 64 + j * 16 + lr];
#pragma unroll
    for (int i = 0; i < 4; ++i)
#pragma unroll
        for (int r = 0; r < 4; ++r) {
            int row = rowBase + wm * 64 + i * 16 + quad * 4 + r;   // D row
#pragma unroll
            for (int j = 0; j < 4; ++j) {
                int col = wn * 64 + j * 16 + lr;                    // D col
                stC(&Ct[(size_t)row * ldC + col], acc[i][j][r] + bj[j]);
            }
        }
}

// val (2 col-tiles) + off (2) + attn (1), all f16 out: grid (340, 5)
__global__ __launch_bounds__(256) void gemm_fused(const float* __restrict__ inputf,
                                                  const float* __restrict__ query,
                                                  const ushort_t* __restrict__ wb,
                                                  const float* __restrict__ b_val,
                                                  const float* __restrict__ b_off,
                                                  const float* __restrict__ b_attn,
                                                  __half* __restrict__ bval,
                                                  __half* __restrict__ v_off,
                                                  __half* __restrict__ v_attn) {
    const int gy = blockIdx.y;
    const int rowBase = blockIdx.x * 128;
    if (gy < 2)
        gemm_core<float, __half>(inputf, wb + WVAL + (size_t)gy * 128 * DIM,
                                 b_val + gy * 128, bval + gy * 128, DIM, rowBase);
    else if (gy < 4)
        gemm_core<float, __half>(query, wb + WOFF + (size_t)(gy - 2) * 128 * DIM,
                                 b_off + (gy - 2) * 128, v_off + (gy - 2) * 128, DIM,
                                 rowBase);
    else
        gemm_core<float, __half>(query, wb + WATT, b_attn, v_attn, 128, rowBase);
}

__global__ __launch_bounds__(256) void gemm_out(const ushort_t* __restrict__ A,
                                                const ushort_t* __restrict__ wb,
                                                const float* __restrict__ bias,
                                                float* __restrict__ C) {
    gemm_core<ushort_t, float>(A, wb + WOUT + (size_t)blockIdx.y * 128 * DIM,
                               bias + blockIdx.y * 128, C + blockIdx.y * 128, DIM,
                               blockIdx.x * 128);
}

// One block per 4 queries, 128 threads. XCD-aware: batch n = blockIdx.x & 7
// matches the round-robin block->XCD mapping, so each XCD's L2 holds one
// batch's value plane (2.8 MB f16 < 4 MB L2).
// Phase A (128 thr x 4 items = 512 = q4*h*l*p): coords + softmax + corner BYTE
//   offsets + packed-half2 weights -> LDS at slot = item idx (16B b128 writes).
// Phase B: thread = (q4, h, cg): 8 f16 channels per corner via uint4 loads;
//   4 v_pk_fma_f16 per corner; f32 flush every 4 iterations.
__global__ __launch_bounds__(128) void sample_kernel(
    const float* __restrict__ refp,            // (N, Lq, L, 2)
    const __half* __restrict__ off,            // (N*Lq, 256) f16
    const __half* __restrict__ attn,           // (N*Lq, 128) f16
    const __half* __restrict__ bval,           // (N, Lin, 256) f16, d = h*32+c
    const int* __restrict__ shapes,            // (L, 2) [H, W]
    const int* __restrict__ starts,            // (L,)
    ushort_t* __restrict__ sampb)              // (N*Lq, 256) bf16
{
    const int n = blockIdx.x & 7;
    const int qBase = n * NQ + (blockIdx.x >> 3) * 4;
    const int t = threadIdx.x;

    __shared__ __align__(16) int     sidx[512][4];   // 8 KB
    __shared__ __align__(16) __half2 sww[512][4];    // 8 KB

#pragma unroll
    for (int it = 0; it < 4; ++it) {
        const int i = t + it * 128;
        const int q4 = i >> 7, hlp = i & 127;
        const int h = hlp >> 4, lp = hlp & 15, l = lp >> 2;
        const int q = qBase + q4;
        const int Wl = shapes[2 * l + 1], Hl = shapes[2 * l];
        const float Wf = (float)Wl, Hf = (float)Hl;
        const float2 rp = *(const float2*)(refp + ((size_t)q * NLV + l) * 2);
        const __half2 oo2 = ((const __half2*)off)[(size_t)q * 128 + h * 16 + lp];
        const float2 oo = __half22float2(oo2);
        const float x = (rp.x + oo.x / Wf) * Wf - 0.5f;
        const float y = (rp.y + oo.y / Hf) * Hf - 0.5f;

        float logit = __half2float(attn[(size_t)q * 128 + h * 16 + lp]);
        float m = logit;
#pragma unroll
        for (int s = 8; s >= 1; s >>= 1) m = fmaxf(m, __shfl_xor(m, s, 16));
        float e = __expf(logit - m);
        float ss = e;
#pragma unroll
        for (int s = 8; s >= 1; s >>= 1) ss += __shfl_xor(ss, s, 16);
        const float aw = e / ss;

        const float xf = floorf(x), yf = floorf(y);
        const int ix = (int)xf, iy = (int)yf;
        const float wx = x - xf, wy = y - yf;
        const int ix1 = ix + 1, iy1 = iy + 1;
        const bool bx0 = (ix >= 0) & (ix < Wl);
        const bool bx1 = (ix1 >= 0) & (ix1 < Wl);
        const bool by0 = (iy >= 0) & (iy < Hl);
        const bool by1 = (iy1 >= 0) & (iy1 < Hl);
        const int cx0 = min(max(ix, 0), Wl - 1), cx1 = min(max(ix1, 0), Wl - 1);
        const int cy0 = min(max(iy, 0), Hl - 1), cy1 = min(max(iy1, 0), Hl - 1);
        const int base = n * NQ + starts[l];
        int4 id;
        id.x = (base + cy0 * Wl + cx0) << 9;   // byte offset (row stride 512B)
        id.y = (base + cy0 * Wl + cx1) << 9;
        id.z = (base + cy1 * Wl + cx0) << 9;
        id.w = (base + cy1 * Wl + cx1) << 9;
        __half2 wp[4];
        wp[0] = __float2half2_rn((bx0 && by0) ? aw * (1.f - wx) * (1.f - wy) : 0.f);
        wp[1] = __float2half2_rn((bx1 && by0) ? aw * wx * (1.f - wy) : 0.f);
        wp[2] = __float2half2_rn((bx0 && by1) ? aw * (1.f - wx) * wy : 0.f);
        wp[3] = __float2half2_rn((bx1 && by1) ? aw * wx * wy : 0.f);
        *(int4*)sidx[i] = id;
        *(uint4*)&sww[i][0] = *(uint4*)wp;
    }
    __syncthreads();

    const int q4 = t >> 5, r = t & 31;
    const int h = r >> 2, cg = r & 3;           // 8 channels per thread
    const int q = qBase + q4;
    const char* vb = (const char*)bval + h * 64 + cg * 16;

    __half2 acch[4];
    float accf[8];
#pragma unroll
    for (int e = 0; e < 4; ++e) acch[e] = __float2half2_rn(0.f);
#pragma unroll
    for (int e = 0; e < 8; ++e) accf[e] = 0.f;

#pragma unroll
    for (int j = 0; j < 16; ++j) {
        const int lp = (j + h) & 15;            // per-head rotation: 2-way max alias
        const int slot = (q4 << 7) + (h << 4) + lp;
        const int4 id = *(const int4*)sidx[slot];
        uint4 wu = *(const uint4*)&sww[slot][0];
        const __half2* wp = (const __half2*)&wu;
        int idc[4] = {id.x, id.y, id.z, id.w};
#pragma unroll
        for (int c = 0; c < 4; ++c) {
            const uint4 u = *(const uint4*)(vb + (size_t)(unsigned)idc[c]);
            const __half2* hv = (const __half2*)&u;
#pragma unroll
            for (int e = 0; e < 4; ++e) acch[e] = __hfma2(hv[e], wp[c], acch[e]);
        }
        if ((j & 3) == 3) {
#pragma unroll
            for (int e = 0; e < 4; ++e) {
                float2 f = __half22float2(acch[e]);
                accf[2 * e] += f.x;
                accf[2 * e + 1] += f.y;
                acch[e] = __float2half2_rn(0.f);
            }
        }
    }

    s16x8 o;
#pragma unroll
    for (int e = 0; e < 8; ++e) o[e] = f2bf(accf[e]);
    *(s16x8*)(sampb + (size_t)q * DIM + h * CHN + cg * 8) = o;
}

extern "C" void kernel_launch(void* const* d_in, const int* in_sizes, int n_in,
                              void* d_out, int out_size, void* d_ws, size_t ws_size,
                              hipStream_t stream) {
    const float* query  = (const float*)d_in[0];
    const float* refp   = (const float*)d_in[1];
    const float* inputf = (const float*)d_in[2];
    const int* shapes   = (const int*)d_in[3];
    const int* starts   = (const int*)d_in[4];
    const float* W_off  = (const float*)d_in[5];
    const float* b_off  = (const float*)d_in[6];
    const float* W_attn = (const float*)d_in[7];
    const float* b_attn = (const float*)d_in[8];
    const float* W_val  = (const float*)d_in[9];
    const float* b_val  = (const float*)d_in[10];
    const float* W_out  = (const float*)d_in[11];
    const float* b_out  = (const float*)d_in[12];
    float* out = (float*)d_out;

    // workspace (bytes): wb(bf16) | bval(f16) | v_off(f16) | v_attn(f16) | sampb(bf16)
    const size_t AB = (size_t)MTOT * DIM * 2;   // 22,282,240
    char* ws = (char*)d_ws;
    ushort_t* wb     = (ushort_t*)ws;                                   // 0.46 MB
    __half*   bval   = (__half*)(ws + 512 * 1024);
    __half*   v_off  = (__half*)(ws + 512 * 1024 + AB);
    __half*   v_attn = (__half*)(ws + 512 * 1024 + 2 * AB);
    ushort_t* sampb  = (ushort_t*)(ws + 512 * 1024 + 2 * AB + AB / 2);

    cvt_weights<<<dim3(WTOT / 2048), dim3(256), 0, stream>>>(W_val, W_off, W_attn,
                                                             W_out, wb);
    gemm_fused<<<dim3(MTOT / 128, 5), dim3(256), 0, stream>>>(
        inputf, query, wb, b_val, b_off, b_attn, bval, v_off, v_attn);
    sample_kernel<<<dim3(MTOT / 4), dim3(128), 0, stream>>>(
        refp, v_off, v_attn, bval, shapes, starts, sampb);
    gemm_out<<<dim3(MTOT / 128, 2), dim3(256), 0, stream>>>(sampb, wb, b_out, out);
}